// Round 6
// baseline (168.380 us; speedup 1.0000x reference)
//
#include <hip/hip_runtime.h>
#include <cstdint>

// Problem constants (static shapes from reference)
#define NBI 128
#define NBC 128
#define NR_ 36
#define NW_ 50
#define EMB_ 1024
#define MTOT (NBI * NR_)   // 4608
#define NTOT (NBC * NW_)   // 6400
#define OUTN (NBI * NBC * NW_)  // 819200

typedef _Float16 f16;
typedef _Float16 f16x8 __attribute__((ext_vector_type(8)));
typedef float f32x4 __attribute__((ext_vector_type(4)));

// ---------------- monotonic float<->uint mapping for atomicMax ----------------
// fkey is strictly monotonic over all finite floats; fkey(finite) != 0, so the
// zero-init of `mono` is a safe "no contribution yet" sentinel.
__device__ __forceinline__ uint32_t fkey(float v) {
  int32_t b = __float_as_int(v);
  return (b >= 0) ? ((uint32_t)b | 0x80000000u) : ~(uint32_t)b;
}

// ---------------- zero the mono buffer (vectorized) ----------------
__global__ void zero_kernel(uint4* __restrict__ p, int n4) {
  int i = blockIdx.x * 256 + threadIdx.x;
  if (i < n4) p[i] = uint4{0u, 0u, 0u, 0u};
}

// ---------------- f32 -> f16 conversion, A and B fused (8 elems/thread) ----------------
__global__ void cvt_kernel(const float* __restrict__ srcA, f16* __restrict__ dstA, int nA8,
                           const float* __restrict__ srcB, f16* __restrict__ dstB, int nB8) {
  int i = blockIdx.x * 256 + threadIdx.x;
  const float* src;
  f16* dst;
  if (i < nA8) {
    src = srcA; dst = dstA;
  } else {
    i -= nA8;
    if (i >= nB8) return;
    src = srcB; dst = dstB;
  }
  const float4* s = (const float4*)src;
  float4 a = s[2 * i];
  float4 b = s[2 * i + 1];
  union { f16 h[8]; uint4 u; } r;
  r.h[0] = (f16)a.x; r.h[1] = (f16)a.y; r.h[2] = (f16)a.z; r.h[3] = (f16)a.w;
  r.h[4] = (f16)b.x; r.h[5] = (f16)b.y; r.h[6] = (f16)b.z; r.h[7] = (f16)b.w;
  ((uint4*)dst)[i] = r.u;
}

// ---------------- fused GEMM + masked region-maxpool ----------------
// Big-GEMM view: A [4608 x 1024] f16 (row = i*36 + r), B [6400 x 1024] f16
// (row = c*50 + w). C = A * B^T, maxpool over region rows per image.
// BM=BN=128, BK=64, 4 waves, wave tile 64x64 (4x4 MFMA 16x16x32_f16 tiles).
// launch_bounds(256,3): VGPR cap 170 -> target 3 blocks/CU (m97 occupancy).
__launch_bounds__(256, 3)
__global__ void gemm_max_kernel(const f16* __restrict__ A, const f16* __restrict__ B,
                                const int* __restrict__ img_lens,
                                uint32_t* __restrict__ mono) {
  __shared__ unsigned char smem[32768];  // A tile 16KB @0, B tile 16KB @16384

  // Block remap for L2 locality:
  //  1) XCD swizzle (T1): 1800 = 8 * 225, each XCD gets a contiguous logical range.
  //  2) Supertile: 5 supercolumns x (36 bm x 10 bn) so a sweep's working set
  //     (A panel 9.2MB + 10 B tiles 2.6MB) stays cache-hot per XCD L2 sweep.
  const int bx = blockIdx.x;
  const int L = (bx & 7) * 225 + (bx >> 3);  // bijective, 1800 = 8*225
  const int sc = L / 360;                    // supercolumn 0..4
  const int rem = L - sc * 360;
  const int bm = rem % 36;                   // 0..35  (M block)
  const int bn = sc * 10 + rem / 36;         // 0..49  (N block)

  const int t = threadIdx.x;
  const int lane = t & 63;
  const int wv = t >> 6;        // wave 0..3
  const int wr = wv >> 1;       // wave row 0..1
  const int wc = wv & 1;        // wave col 0..1

  f32x4 acc[4][4] = {};

  const char* Ab = (const char*)A + (size_t)(bm * 128) * 2048;  // row stride 1024 f16 = 2048B
  const char* Bb = (const char*)B + (size_t)(bn * 128) * 2048;

  // Staging: per BK=64 chunk each tile is 128 rows x 128 bytes = 1024 16B-units.
  // Thread t stages units {t, t+256, t+512, t+768}. LDS dest is LINEAR
  // (global_load_lds: per-wave dest = uniform base + lane*16; u*16 satisfies
  // this within each wave). The XOR swizzle (byte ^= (row&7)<<4) is applied on
  // the GLOBAL source address, and the same involution on the ds_read side
  // (rule #21: both-sides-or-neither).
  int sdst[4];
  int sgof[4];
#pragma unroll
  for (int j = 0; j < 4; ++j) {
    int u = t + 256 * j;
    int row = u >> 3;                 // 0..127
    int phys = (u & 7) * 16;          // physical byte-in-row (LDS)
    int logical = phys ^ ((row & 7) << 4);  // source byte-in-chunk (global)
    sdst[j] = u * 16;
    sgof[j] = row * 2048 + logical;
  }

  for (int ck = 0; ck < 16; ++ck) {
    const int k0b = ck * 128;  // chunk byte offset within a row
#pragma unroll
    for (int j = 0; j < 4; ++j) {
      __builtin_amdgcn_global_load_lds(
          (const __attribute__((address_space(1))) void*)(Ab + (size_t)sgof[j] + k0b),
          (__attribute__((address_space(3))) void*)(smem + sdst[j]), 16, 0, 0);
    }
#pragma unroll
    for (int j = 0; j < 4; ++j) {
      __builtin_amdgcn_global_load_lds(
          (const __attribute__((address_space(1))) void*)(Bb + (size_t)sgof[j] + k0b),
          (__attribute__((address_space(3))) void*)(smem + 16384 + sdst[j]), 16, 0, 0);
    }
    __syncthreads();  // compiler drains vmcnt(0) before s_barrier: staged data visible

#pragma unroll
    for (int kk = 0; kk < 2; ++kk) {
      f16x8 af[4], bf[4];
#pragma unroll
      for (int mt = 0; mt < 4; ++mt) {
        int row = wr * 64 + mt * 16 + (lane & 15);
        int col = (kk * 64 + (lane >> 4) * 16) ^ ((row & 7) << 4);
        af[mt] = *(const f16x8*)(smem + row * 128 + col);
      }
#pragma unroll
      for (int nt = 0; nt < 4; ++nt) {
        int row = wc * 64 + nt * 16 + (lane & 15);
        int col = (kk * 64 + (lane >> 4) * 16) ^ ((row & 7) << 4);
        bf[nt] = *(const f16x8*)(smem + 16384 + row * 128 + col);
      }
      // Bank check: within a 16-lane group, rows r0..r0+15 -> (row&7) hits each
      // value twice; paired rows differ by 8 rows = 1024B = bank-period -> 2
      // lanes/bank = free (m136).
#pragma unroll
      for (int mt = 0; mt < 4; ++mt)
#pragma unroll
        for (int nt = 0; nt < 4; ++nt)
          acc[mt][nt] = __builtin_amdgcn_mfma_f32_16x16x32_f16(af[mt], bf[nt], acc[mt][nt], 0, 0, 0);
    }
    __syncthreads();  // all waves done reading before next stage overwrites
  }

  // ---------------- epilogue: masked maxpool over region rows ----------------
  // D tile layout (m89-verified): row = (lane>>4)*4 + reg, col = lane&15.
  const int g0 = bm * 128 + wr * 64;          // wave's first global M row
  const int i_first = g0 / 36;
  const int i_last = (g0 + 63) / 36;          // <=3 images per wave

#pragma unroll
  for (int nt = 0; nt < 4; ++nt) {
    const int col_g = bn * 128 + wc * 64 + nt * 16 + (lane & 15);  // = c*50 + w
    for (int tgt = i_first; tgt <= i_last; ++tgt) {
      const int len = img_lens[tgt];
      float v = -3.0e38f;
#pragma unroll
      for (int mt = 0; mt < 4; ++mt) {
#pragma unroll
        for (int r4 = 0; r4 < 4; ++r4) {
          int gr = g0 + mt * 16 + ((lane >> 4) << 2) + r4;
          int ii = gr / 36;
          int rr = gr - ii * 36;
          if (ii == tgt && rr < len) v = fmaxf(v, acc[mt][nt][r4]);
        }
      }
      // column-wise reduce across the 4 row-groups (lanes l, l^16, l^32, l^48)
      v = fmaxf(v, __shfl_xor(v, 16));
      v = fmaxf(v, __shfl_xor(v, 32));
      if ((lane >> 4) == 0 && v > -2.9e38f) {
        atomicMax(&mono[(size_t)tgt * 6400 + col_g], fkey(v));
      }
    }
  }
}

// ---------------- finalize: decode + exact reference masking ----------------
__global__ void finalize_kernel(const uint32_t* __restrict__ mono,
                                const int* __restrict__ img_lens,
                                const int* __restrict__ cap_lens,
                                float* __restrict__ out) {
  int idx = blockIdx.x * 256 + threadIdx.x;
  if (idx >= OUTN) return;
  int i = idx / (NBC * NW_);
  int rem = idx - i * (NBC * NW_);
  int c = rem / NW_;
  int w = rem - c * NW_;
  uint32_t k = mono[idx];
  int32_t b = (k & 0x80000000u) ? (int32_t)(k & 0x7FFFFFFFu) : (int32_t)~k;
  float v = __int_as_float(b);
  // masked (r >= len) entries are filled with -1 and participate in the max
  if (img_lens[i] < NR_) v = fmaxf(v, -1.0f);
  // invalid words: entire column is -1
  if (w >= cap_lens[c]) v = -1.0f;
  out[idx] = v;
}

extern "C" void kernel_launch(void* const* d_in, const int* in_sizes, int n_in,
                              void* d_out, int out_size, void* d_ws, size_t ws_size,
                              hipStream_t stream) {
  const float* imgs = (const float*)d_in[0];
  const float* caps = (const float*)d_in[1];
  const int* img_lens = (const int*)d_in[2];
  const int* cap_lens = (const int*)d_in[3];
  float* out = (float*)d_out;

  char* ws = (char*)d_ws;
  f16* Af = (f16*)ws;                                        // 4608*1024*2 = 9.44 MB
  f16* Bf = (f16*)(ws + (size_t)MTOT * EMB_ * 2);            // 6400*1024*2 = 13.1 MB
  uint32_t* mono = (uint32_t*)(ws + (size_t)MTOT * EMB_ * 2 + (size_t)NTOT * EMB_ * 2);  // 3.3 MB

  const int nA8 = MTOT * EMB_ / 8;  // 589824
  const int nB8 = NTOT * EMB_ / 8;  // 819200
  const int ncvt = nA8 + nB8;       // 1409024

  zero_kernel<<<(OUTN / 4 + 255) / 256, 256, 0, stream>>>((uint4*)mono, OUTN / 4);
  cvt_kernel<<<(ncvt + 255) / 256, 256, 0, stream>>>(imgs, Af, nA8, caps, Bf, nB8);
  gemm_max_kernel<<<36 * 50, 256, 0, stream>>>(Af, Bf, img_lens, mono);
  finalize_kernel<<<(OUTN + 255) / 256, 256, 0, stream>>>(mono, img_lens, cap_lens, out);
}

// Round 7
// 152.373 us; speedup vs baseline: 1.1051x; 1.1051x over previous
//
#include <hip/hip_runtime.h>
#include <cstdint>

// Problem constants (static shapes from reference)
#define NBI 128
#define NBC 128
#define NR_ 36
#define NW_ 50
#define EMB_ 1024
#define MTOT (NBI * NR_)   // 4608
#define NTOT (NBC * NW_)   // 6400

typedef _Float16 f16;
typedef _Float16 f16x8 __attribute__((ext_vector_type(8)));
typedef float f32x4 __attribute__((ext_vector_type(4)));

// ---------------- f32 -> f16 conversion, A and B fused (8 elems/thread) ----------------
__global__ void cvt_kernel(const float* __restrict__ srcA, f16* __restrict__ dstA, int nA8,
                           const float* __restrict__ srcB, f16* __restrict__ dstB, int nB8) {
  int i = blockIdx.x * 256 + threadIdx.x;
  const float* src;
  f16* dst;
  if (i < nA8) {
    src = srcA; dst = dstA;
  } else {
    i -= nA8;
    if (i >= nB8) return;
    src = srcB; dst = dstB;
  }
  const float4* s = (const float4*)src;
  float4 a = s[2 * i];
  float4 b = s[2 * i + 1];
  union { f16 h[8]; uint4 u; } r;
  r.h[0] = (f16)a.x; r.h[1] = (f16)a.y; r.h[2] = (f16)a.z; r.h[3] = (f16)a.w;
  r.h[4] = (f16)b.x; r.h[5] = (f16)b.y; r.h[6] = (f16)b.z; r.h[7] = (f16)b.w;
  ((uint4*)dst)[i] = r.u;
}

// ---------------- fused GEMM + masked region-maxpool, DIRECT output ----------------
// BM=144 = 4 whole images (4*36) -> each block owns images 4*bm..4*bm+3 fully.
// No atomics / mono buffer / finalize: block computes the masked region-max and
// writes final floats. BN=128, BK=64, 4 waves in 1Mx4N split: wave = 144x32 =
// acc[9][2] 16x16 tiles, 36 MFMA per K-chunk. LDS: A 144x128B=18KB @0,
// B 128x128B=16KB @18432 (34816 B total).
__launch_bounds__(256, 3)
__global__ void gemm_max_kernel(const f16* __restrict__ A, const f16* __restrict__ B,
                                const int* __restrict__ img_lens,
                                const int* __restrict__ cap_lens,
                                float* __restrict__ out) {
  __shared__ unsigned char smem[34816];

  // Block remap: XCD swizzle (1600 = 8*200, bijective) + supertile
  // (5 supercolumns x (32 bm x 10 bn)) for L2 locality.
  const int bx = blockIdx.x;
  const int L = (bx & 7) * 200 + (bx >> 3);
  const int sc = L / 320;                    // 0..4
  const int rem = L - sc * 320;
  const int bm = rem & 31;                   // 0..31 (M block: 144 rows = 4 images)
  const int bn = sc * 10 + (rem >> 5);       // 0..49

  const int t = threadIdx.x;
  const int lane = t & 63;
  const int wv = t >> 6;                     // wave 0..3 -> cols [wv*32, wv*32+32)

  f32x4 acc[9][2] = {};

  const char* Ab = (const char*)A + (size_t)(bm * 144) * 2048;  // row = 1024 f16 = 2048B
  const char* Bb = (const char*)B + (size_t)(bn * 128) * 2048;

  // Staging: per BK=64 chunk, A = 144 rows x 8 16B-units = 1152 units,
  // B = 128 x 8 = 1024 units. Thread t stages A units {t+256j, j=0..3} and
  // (t<128 only, wave-uniform) unit t+1024; B units {t+256j}.
  // LDS dest LINEAR (wave-uniform base + lane*16); XOR swizzle (row&7)<<4 is
  // applied on the GLOBAL source and again on the ds_read side (rule #21).
  int sdstA[5], sgofA[5];
#pragma unroll
  for (int j = 0; j < 5; ++j) {
    int u = t + 256 * j;                  // j==4 only used when t<128 -> u in [1024,1152)
    int row = u >> 3;
    int phys = (u & 7) * 16;
    int logical = phys ^ ((row & 7) << 4);
    sdstA[j] = u * 16;
    sgofA[j] = row * 2048 + logical;
  }
  int sdstB[4], sgofB[4];
#pragma unroll
  for (int j = 0; j < 4; ++j) {
    int u = t + 256 * j;
    int row = u >> 3;
    int phys = (u & 7) * 16;
    int logical = phys ^ ((row & 7) << 4);
    sdstB[j] = 18432 + u * 16;
    sgofB[j] = row * 2048 + logical;
  }

  for (int ck = 0; ck < 16; ++ck) {
    const int k0b = ck * 128;
#pragma unroll
    for (int j = 0; j < 4; ++j) {
      __builtin_amdgcn_global_load_lds(
          (const __attribute__((address_space(1))) void*)(Ab + (size_t)sgofA[j] + k0b),
          (__attribute__((address_space(3))) void*)(smem + sdstA[j]), 16, 0, 0);
    }
    if (t < 128) {  // waves 0,1 only: rows 128..143 (wave-uniform branch)
      __builtin_amdgcn_global_load_lds(
          (const __attribute__((address_space(1))) void*)(Ab + (size_t)sgofA[4] + k0b),
          (__attribute__((address_space(3))) void*)(smem + sdstA[4]), 16, 0, 0);
    }
#pragma unroll
    for (int j = 0; j < 4; ++j) {
      __builtin_amdgcn_global_load_lds(
          (const __attribute__((address_space(1))) void*)(Bb + (size_t)sgofB[j] + k0b),
          (__attribute__((address_space(3))) void*)(smem + sdstB[j]), 16, 0, 0);
    }
    __syncthreads();  // vmcnt(0) drained before barrier: staged data visible

#pragma unroll
    for (int kk = 0; kk < 2; ++kk) {
      f16x8 af[9], bf[2];
#pragma unroll
      for (int mt = 0; mt < 9; ++mt) {
        int row = mt * 16 + (lane & 15);
        int col = (kk * 64 + (lane >> 4) * 16) ^ ((row & 7) << 4);
        af[mt] = *(const f16x8*)(smem + row * 128 + col);
      }
#pragma unroll
      for (int nt = 0; nt < 2; ++nt) {
        int row = wv * 32 + nt * 16 + (lane & 15);
        int col = (kk * 64 + (lane >> 4) * 16) ^ ((row & 7) << 4);
        bf[nt] = *(const f16x8*)(smem + 18432 + row * 128 + col);
      }
#pragma unroll
      for (int mt = 0; mt < 9; ++mt)
#pragma unroll
        for (int nt = 0; nt < 2; ++nt)
          acc[mt][nt] = __builtin_amdgcn_mfma_f32_16x16x32_f16(af[mt], bf[nt], acc[mt][nt], 0, 0, 0);
    }
    __syncthreads();
  }

  // ---------------- epilogue: per-image masked max + direct store ----------------
  // D layout (m89): local row = mt*16 + (lane>>4)*4 + r4, col = lane&15.
  const int q4 = ((lane >> 4) << 2);
  const int cg0 = bn * 128 + wv * 32 + (lane & 15);        // nt=0 global col
  const int cg1 = cg0 + 16;                                 // nt=1 global col
  const int c0 = cg0 / 50, w0 = cg0 - 50 * c0;
  const int c1 = cg1 / 50, w1 = cg1 - 50 * c1;
  const int cap0 = cap_lens[c0], cap1 = cap_lens[c1];

#pragma unroll
  for (int k = 0; k < 4; ++k) {
    const int gi = bm * 4 + k;
    const int len = img_lens[gi];             // 1..36
    const int lo = 36 * k, hi = 36 * k + len;
    float v0 = -3.0e38f, v1 = -3.0e38f;
#pragma unroll
    for (int mt = 0; mt < 9; ++mt) {
#pragma unroll
      for (int r4 = 0; r4 < 4; ++r4) {
        int row = mt * 16 + q4 + r4;
        if (row >= lo && row < hi) {          // valid region row of image k
          v0 = fmaxf(v0, acc[mt][0][r4]);
          v1 = fmaxf(v1, acc[mt][1][r4]);
        }
      }
    }
    // reduce across the 4 row-groups (lanes l, l^16, l^32, l^48 share a col)
    v0 = fmaxf(v0, __shfl_xor(v0, 16)); v0 = fmaxf(v0, __shfl_xor(v0, 32));
    v1 = fmaxf(v1, __shfl_xor(v1, 16)); v1 = fmaxf(v1, __shfl_xor(v1, 32));
    // reference semantics: -1 fill participates in region-max iff len<36
    if (len < NR_) { v0 = fmaxf(v0, -1.0f); v1 = fmaxf(v1, -1.0f); }
    if (lane < 16) {
      float o0 = (w0 >= cap0) ? -1.0f : v0;   // invalid word -> -1
      float o1 = (w1 >= cap1) ? -1.0f : v1;
      out[(size_t)gi * 6400 + cg0] = o0;
      out[(size_t)gi * 6400 + cg1] = o1;
    }
  }
}

extern "C" void kernel_launch(void* const* d_in, const int* in_sizes, int n_in,
                              void* d_out, int out_size, void* d_ws, size_t ws_size,
                              hipStream_t stream) {
  const float* imgs = (const float*)d_in[0];
  const float* caps = (const float*)d_in[1];
  const int* img_lens = (const int*)d_in[2];
  const int* cap_lens = (const int*)d_in[3];
  float* out = (float*)d_out;

  char* ws = (char*)d_ws;
  f16* Af = (f16*)ws;                              // 4608*1024*2 = 9.44 MB
  f16* Bf = (f16*)(ws + (size_t)MTOT * EMB_ * 2);  // 6400*1024*2 = 13.1 MB

  const int nA8 = MTOT * EMB_ / 8;  // 589824
  const int nB8 = NTOT * EMB_ / 8;  // 819200
  const int ncvt = nA8 + nB8;

  cvt_kernel<<<(ncvt + 255) / 256, 256, 0, stream>>>(imgs, Af, nA8, caps, Bf, nB8);
  gemm_max_kernel<<<32 * 50, 256, 0, stream>>>(Af, Bf, img_lens, cap_lens, out);
}